// Round 1
// baseline (140.661 us; speedup 1.0000x reference)
//
#include <hip/hip_runtime.h>

// Rec1_43748536877661 — diagonal SSM block, MI355X gfx950.
// B=2,S=2048,D=128,N=2048. fp32 in/out, bf16 MFMA compute (tol 2.14e-2).
// R10: R9 structure, occupancy fix. R9 capped projscan at
// __launch_bounds__(256,2) -> 2 blocks/CU -> only 512 of 1024 blocks
// co-resident -> grid ran as TWO sequential rounds (rocprof: Occupancy 17.8%,
// MfmaUtil 5%, VALUBusy 22%, HBM 7% - nothing saturated, residency-bound).
// LDS (31232B -> 5 blk/CU) and VGPR (88 -> 5 blk/CU) both allow 4 blocks/CU;
// (256,4) makes all 1024 blocks (= 256 CU x 4) co-resident: one round, one
// set of lookback chains, 2x latency-hiding waves in Phase A.
//  1. prep      pack x,W_B/dt/C,W_out fragment-linear bf16; Aval; zero Sbuf tags
//  2. projscan  grid(16,64): 16 t-tiles x 32 n per block; GEMM+scan local,
//               tagged-atomic lookback, in-register fixup -> y (bf16 A-frag)
//  3. outproj   y @ W_out^T + b_out -> fp32 out
// Deadlock safety: waits only target lower-bx blocks of the SAME by-row;
// in-order dispatch + retirement means predecessors are always resident or
// done; chains bottom out at bx%8==0 (no wait).

#define BB 2
#define SS 2048
#define DDIM 128
#define NDIM 2048
#define TT (BB*SS)        // 4096 tokens
#define NTILE (TT/16)     // 256 t-tiles

typedef short short8 __attribute__((ext_vector_type(8)));
typedef float floatx4 __attribute__((ext_vector_type(4)));

__device__ __forceinline__ unsigned short f2b(float f){
  unsigned u = __float_as_uint(f);
  u += 0x7FFFu + ((u >> 16) & 1u);
  return (unsigned short)(u >> 16);
}
__device__ __forceinline__ float softplus_f(float v){
  return v > 15.f ? v : __logf(1.f + __expf(v));
}
__device__ __forceinline__ void pack8(const float* __restrict__ s,
                                      unsigned short* __restrict__ d){
  floatx4 v0 = *(const floatx4*)s;
  floatx4 v1 = *(const floatx4*)(s + 4);
  short8 r;
  r[0]=(short)f2b(v0[0]); r[1]=(short)f2b(v0[1]); r[2]=(short)f2b(v0[2]); r[3]=(short)f2b(v0[3]);
  r[4]=(short)f2b(v1[0]); r[5]=(short)f2b(v1[1]); r[6]=(short)f2b(v1[2]); r[7]=(short)f2b(v1[3]);
  *(short8*)d = r;
}

// ---------------- 1. prep ----------------
__global__ void prep_kernel(const float* __restrict__ x,
                            const float* __restrict__ W_B,
                            const float* __restrict__ W_C,
                            const float* __restrict__ W_dt,
                            const float* __restrict__ A_log,
                            const float* __restrict__ W_out,
                            unsigned short* __restrict__ xp,
                            unsigned short* __restrict__ Wp3,
                            unsigned short* __restrict__ Wop,
                            float* __restrict__ Aval,
                            unsigned long long* __restrict__ Sbuf){
  const int gid = blockIdx.x * blockDim.x + threadIdx.x;   // 0..98303
  if (gid < 32768) Sbuf[gid] = 0ull;              // clear tags (1024 x 32)
  if (gid < 2048) Aval[gid] = -__expf(A_log[gid]);
  if (gid < 65536){                               // x: 256 t-tiles, K=128
    int g = gid, tile = g >> 8, kk = (g >> 6) & 3, lane = g & 63;
    int q = lane >> 4, m = lane & 15;
    pack8(x + (size_t)(tile*16 + m)*DDIM + kk*32 + q*8, xp + (size_t)g*8);
  }
  if (gid < 98304){                               // W_B/W_dt/W_C: 128 n-tiles each
    int mat = gid >> 15, g = gid & 32767;
    const float* W = (mat == 0) ? W_B : (mat == 1 ? W_dt : W_C);
    int tile = g >> 8, kk = (g >> 6) & 3, lane = g & 63;
    int q = lane >> 4, m = lane & 15;
    pack8(W + (size_t)(tile*16 + m)*DDIM + kk*32 + q*8,
          Wp3 + (size_t)mat*262144 + (size_t)g*8);
  }
  if (gid < 32768){                               // W_out: 8 d-tiles, K=2048
    int g = gid, tile = g >> 12, kk = (g >> 6) & 63, lane = g & 63;
    int q = lane >> 4, m = lane & 15;
    pack8(W_out + (size_t)(tile*16 + m)*NDIM + kk*32 + q*8, Wop + (size_t)g*8);
  }
}

// ---------------- 2. projscan with tagged-atomic lookback ----------------
// grid (16, 64), block 256. bx = t-chunk (16 tiles), by = 32-n slice.
// Wave wv handles tiles bx*16 + wv*4 .. +4. bx%8==0 starts a batch (h=0).
// __launch_bounds__(256,4): 4 waves/EU -> 16 waves/CU -> 4 blocks/CU ->
// all 1024 blocks co-resident (256 CU x 4). VGPR budget 128 (was using 88).
__global__ __launch_bounds__(256, 4) void projscan_kernel(
    const unsigned short* __restrict__ xp,
    const unsigned short* __restrict__ Wp3,
    const float* __restrict__ b_B,
    const float* __restrict__ b_dt,
    const float* __restrict__ b_C,
    const float* __restrict__ Aval,
    unsigned long long* __restrict__ Sbuf,   // [64*16][32] tagged chain states
    unsigned short* __restrict__ ybp){
  __shared__ unsigned short sW[3*4096];      // 24 KB packed weights (this n-slice)
  __shared__ unsigned short sYT[4][16*40];   // per-wave transpose tile
  __shared__ float sPw[4][32], sHw[4][32];   // per-wave chain totals
  __shared__ float sIw[4][32];               // per-wave init states
  const int tid  = threadIdx.x;
  const int lane = tid & 63;
  const int wv   = tid >> 6;
  const int m    = lane & 15;
  const int q    = lane >> 4;
  const int bx   = blockIdx.x;
  const int by   = blockIdx.y;               // chain id
  const int n0   = by*32;

  // stage packed weights: 3 mats x 2 n-tiles x 2048 ushort
  for (int i = tid; i < 1536; i += 256){
    int mat = i >> 9, rem = i & 511;
    *(short8*)(sW + mat*4096 + rem*8) =
        *(const short8*)(Wp3 + (size_t)mat*262144 + (size_t)by*4096 + rem*8);
  }
  __syncthreads();

  // per-nt biases (n = n0 + nt*16 + m)
  float bBv[2], bDv[2], bCv[2], Avv[2];
#pragma unroll
  for (int nt = 0; nt < 2; ++nt){
    const int n = n0 + nt*16 + m;
    bBv[nt] = b_B[n]; bDv[nt] = b_dt[n]; bCv[nt] = b_C[n]; Avv[nt] = Aval[n];
  }

  // ---- Phase A: 4 sequential tiles, local scan (init 0), keep y/coef packed
  unsigned ypk[4][2][2], cpk[4][2][2];
  float pe_t[4][2], he_t[4][2];
  float pa_run[2] = {1.f, 1.f}, ha_run[2] = {0.f, 0.f};

#pragma unroll
  for (int i = 0; i < 4; ++i){
    const int tile = bx*16 + wv*4 + i;
    short8 xf[4];
#pragma unroll
    for (int kk = 0; kk < 4; ++kk)
      xf[kk] = *(const short8*)(xp + (size_t)tile*2048 + kk*512 + lane*8);

    floatx4 acc[3][2];
#pragma unroll
    for (int mat = 0; mat < 3; ++mat)
#pragma unroll
      for (int nt = 0; nt < 2; ++nt)
        acc[mat][nt] = (floatx4){0.f,0.f,0.f,0.f};
#pragma unroll
    for (int nt = 0; nt < 2; ++nt)
#pragma unroll
      for (int kk = 0; kk < 4; ++kk){
        short8 wB = *(const short8*)(sW +         nt*2048 + kk*512 + lane*8);
        short8 wD = *(const short8*)(sW + 4096 +  nt*2048 + kk*512 + lane*8);
        short8 wC = *(const short8*)(sW + 8192 +  nt*2048 + kk*512 + lane*8);
        acc[0][nt] = __builtin_amdgcn_mfma_f32_16x16x32_bf16(xf[kk], wB, acc[0][nt], 0, 0, 0);
        acc[1][nt] = __builtin_amdgcn_mfma_f32_16x16x32_bf16(xf[kk], wD, acc[1][nt], 0, 0, 0);
        acc[2][nt] = __builtin_amdgcn_mfma_f32_16x16x32_bf16(xf[kk], wC, acc[2][nt], 0, 0, 0);
      }

#pragma unroll
    for (int nt = 0; nt < 2; ++nt){
      float Ar[4], Br[4], Cc[4];
#pragma unroll
      for (int r = 0; r < 4; ++r){
        float dtv = softplus_f(acc[1][nt][r] + bDv[nt]);
        Ar[r] = __expf(dtv * Avv[nt]);
        Br[r] = dtv * (acc[0][nt][r] + bBv[nt]);
        Cc[r] = acc[2][nt][r] + bCv[nt];
      }
      // compose lane's 4-token segment
      float P = Ar[0], H = Br[0];
#pragma unroll
      for (int r = 1; r < 4; ++r){ H = Ar[r]*H + Br[r]; P *= Ar[r]; }
      // inclusive scan across q (2 steps)
      float pp = __shfl(P, (lane - 16) & 63, 64);
      float hh = __shfl(H, (lane - 16) & 63, 64);
      if (q >= 1){ H = P*hh + H; P *= pp; }
      pp = __shfl(P, (lane - 32) & 63, 64);
      hh = __shfl(H, (lane - 32) & 63, 64);
      if (q >= 2){ H = P*hh + H; P *= pp; }
      // exclusive prefix for this q
      float pe = __shfl(P, (lane - 16) & 63, 64);
      float he = __shfl(H, (lane - 16) & 63, 64);
      if (q == 0){ pe = 1.f; he = 0.f; }
      // tile totals broadcast (q==3 inclusive)
      float pb = __shfl(P, m + 48, 64);
      float hb = __shfl(H, m + 48, 64);

      float h = he, pa = pe;
      unsigned short yr[4], cr[4];
#pragma unroll
      for (int r = 0; r < 4; ++r){
        h = Ar[r]*h + Br[r];
        pa *= Ar[r];
        yr[r] = f2b(Cc[r]*h);
        cr[r] = f2b(Cc[r]*pa);
      }
      ypk[i][nt][0] = (unsigned)yr[0] | ((unsigned)yr[1] << 16);
      ypk[i][nt][1] = (unsigned)yr[2] | ((unsigned)yr[3] << 16);
      cpk[i][nt][0] = (unsigned)cr[0] | ((unsigned)cr[1] << 16);
      cpk[i][nt][1] = (unsigned)cr[2] | ((unsigned)cr[3] << 16);

      pe_t[i][nt] = pa_run[nt];
      he_t[i][nt] = ha_run[nt];
      ha_run[nt] = pb*ha_run[nt] + hb;
      pa_run[nt] *= pb;
    }
  }
  // publish wave totals per n (identical across q; q==0 writes)
  if (q == 0){
#pragma unroll
    for (int nt = 0; nt < 2; ++nt){
      sPw[wv][nt*16 + m] = pa_run[nt];
      sHw[wv][nt*16 + m] = ha_run[nt];
    }
  }
  __syncthreads();

  // ---- Phase B: block compose + tagged-atomic lookback (threads 0..31)
  if (tid < 32){
    float Pw[4], Hw[4];
#pragma unroll
    for (int w2 = 0; w2 < 4; ++w2){ Pw[w2] = sPw[w2][tid]; Hw[w2] = sHw[w2][tid]; }
    float Sj = 0.f;
    if (bx & 7){
      unsigned long long* src = Sbuf + (size_t)(by*16 + bx - 1)*32 + tid;
      unsigned long long v;
      for (;;){
        v = __hip_atomic_load(src, __ATOMIC_RELAXED, __HIP_MEMORY_SCOPE_AGENT);
        if ((unsigned)(v >> 32) == 1u) break;
        __builtin_amdgcn_s_sleep(2);
      }
      Sj = __uint_as_float((unsigned)v);
    }
    float s = Sj;
#pragma unroll
    for (int w2 = 0; w2 < 4; ++w2){
      sIw[w2][tid] = s;
      s = Pw[w2]*s + Hw[w2];
    }
    unsigned long long pv = (1ull << 32) | (unsigned long long)__float_as_uint(s);
    __hip_atomic_store(Sbuf + (size_t)(by*16 + bx)*32 + tid, pv,
                       __ATOMIC_RELAXED, __HIP_MEMORY_SCOPE_AGENT);
  }
  __syncthreads();

  // ---- Phase C: fixup + transpose + store
  float iw[2];
#pragma unroll
  for (int nt = 0; nt < 2; ++nt) iw[nt] = sIw[wv][nt*16 + m];
#pragma unroll
  for (int i = 0; i < 4; ++i){
    const int tile = bx*16 + wv*4 + i;
#pragma unroll
    for (int nt = 0; nt < 2; ++nt){
      float it = pe_t[i][nt]*iw[nt] + he_t[i][nt];
#pragma unroll
      for (int j = 0; j < 2; ++j){
        unsigned yp = ypk[i][nt][j], cp = cpk[i][nt][j];
        float y0 = __uint_as_float(yp << 16);
        float y1 = __uint_as_float(yp & 0xffff0000u);
        float c0 = __uint_as_float(cp << 16);
        float c1 = __uint_as_float(cp & 0xffff0000u);
        sYT[wv][(q*4 + j*2 + 0)*40 + nt*16 + m] = f2b(y0 + c0*it);
        sYT[wv][(q*4 + j*2 + 1)*40 + nt*16 + m] = f2b(y1 + c1*it);
      }
    }
    short8 yv = *(const short8*)&sYT[wv][m*40 + q*8];
    *(short8*)(ybp + (size_t)tile*32768 + (size_t)by*512 + (size_t)lane*8) = yv;
  }
}

// ---------------- 3. output projection ----------------
// grid NTILE=256, block 256. Wave wv: kk in [wv*16, wv*16+16), all 8 d-tiles.
__global__ void outproj_kernel(const unsigned short* __restrict__ ybp,
                               const unsigned short* __restrict__ Wop,
                               const float* __restrict__ b_out,
                               float* __restrict__ out){
  __shared__ float red[4*2048];
  const int tid  = threadIdx.x;
  const int lane = tid & 63;
  const int wv   = tid >> 6;
  const int m    = lane & 15;
  const int q    = lane >> 4;
  const int tile = blockIdx.x;

  floatx4 acc[8];
#pragma unroll
  for (int dt = 0; dt < 8; ++dt) acc[dt] = (floatx4){0.f,0.f,0.f,0.f};

  const unsigned short* aP = ybp + (size_t)tile*32768 + lane*8;
  const unsigned short* bP = Wop + (size_t)lane*8;
#pragma unroll 4
  for (int kk = wv*16; kk < wv*16 + 16; ++kk){
    short8 af = *(const short8*)(aP + (size_t)kk*512);
#pragma unroll
    for (int dt = 0; dt < 8; ++dt){
      short8 bf = *(const short8*)(bP + (size_t)dt*32768 + (size_t)kk*512);
      acc[dt] = __builtin_amdgcn_mfma_f32_16x16x32_bf16(af, bf, acc[dt], 0, 0, 0);
    }
  }
#pragma unroll
  for (int dt = 0; dt < 8; ++dt)
#pragma unroll
    for (int r = 0; r < 4; ++r)
      red[wv*2048 + (q*4 + r)*128 + dt*16 + m] = acc[dt][r];
  __syncthreads();
#pragma unroll
  for (int i = 0; i < 8; ++i){
    int idx = i*256 + tid;                        // 0..2047 = tl*128 + d
    float s = red[idx] + red[2048 + idx] + red[4096 + idx] + red[6144 + idx];
    int tl = idx >> 7, d = idx & 127;
    out[(size_t)(tile*16 + tl)*DDIM + d] = s + b_out[d];
  }
}

extern "C" void kernel_launch(void* const* d_in, const int* in_sizes, int n_in,
                              void* d_out, int out_size, void* d_ws, size_t ws_size,
                              hipStream_t stream) {
  const float* x     = (const float*)d_in[0];
  const float* W_B   = (const float*)d_in[1];
  const float* b_B   = (const float*)d_in[2];
  const float* W_C   = (const float*)d_in[3];
  const float* b_C   = (const float*)d_in[4];
  const float* W_dt  = (const float*)d_in[5];
  const float* b_dt  = (const float*)d_in[6];
  const float* A_log = (const float*)d_in[7];
  const float* W_out = (const float*)d_in[8];
  const float* b_out = (const float*)d_in[9];
  float* out = (float*)d_out;

  char* w = (char*)d_ws;
  unsigned short* xp    = (unsigned short*)(w + 0x0000000);  // 1 MB
  unsigned short* Wp3   = (unsigned short*)(w + 0x0100000);  // 1.5 MB
  unsigned short* Wop   = (unsigned short*)(w + 0x0280000);  // 0.5 MB
  float*          Aval  = (float*)         (w + 0x0300000);  // 8 KB
  unsigned short* ybp   = (unsigned short*)(w + 0x0310000);  // 16 MB
  unsigned long long* Sbuf = (unsigned long long*)(w + 0x1310000); // 256 KB
  // total ~19.4 MB

  prep_kernel<<<384, 256, 0, stream>>>(
      x, W_B, W_C, W_dt, A_log, W_out, xp, Wp3, Wop, Aval, Sbuf);

  projscan_kernel<<<dim3(16, 64), 256, 0, stream>>>(
      xp, Wp3, b_B, b_dt, b_C, Aval, Sbuf, ybp);

  outproj_kernel<<<NTILE, 256, 0, stream>>>(ybp, Wop, b_out, out);
}

// Round 2
// 117.627 us; speedup vs baseline: 1.1958x; 1.1958x over previous
//
#include <hip/hip_runtime.h>

// Rec1_43748536877661 — diagonal SSM block, MI355X gfx950.
// B=2,S=2048,D=128,N=2048. fp32 in/out, bf16 MFMA compute (tol 2.14e-2).
// R11: R9 structure + DECOUPLED LOOKBACK. R10 post-mortem: (256,4) squeezed
// VGPR 88->64 -> scratch spill -> 200 MB/dispatch HBM traffic (measured
// 3.73 TB/s == hbm_gbps) -> slower. Reverted to (256,2).
// R9's real limit: serial inclusive-prefix chain (7 hops x ~3us of
// compose+LLC store+spin per 8-block batch row; occupancy 17.8% avg = blocks
// retiring at staggered times). Now every block publishes its LOCAL (P,H)
// aggregate right after Phase A (2 tagged 64-bit relaxed agent atomics);
// block bx reads ALL <=7 predecessors' locals CONCURRENTLY (one LLC
// round-trip, retry-mask loop, fully unrolled static-index regs) and
// composes in-register. Serial chain -> parallel gather.
//  1. prep      pack x,W_B/dt/C,W_out fragment-linear bf16; Aval; zero Sbuf tags
//  2. projscan  grid(16,64): 16 t-tiles x 32 n per block; GEMM+scan local,
//               publish local agg, decoupled lookback, fixup -> y (bf16 A-frag)
//  3. outproj   y @ W_out^T + b_out -> fp32 out
// Deadlock safety: waits only target lower-bx blocks of the SAME by-row
// (lower linear id -> dispatched earlier -> resident or retired); chains
// bottom out at bx%8==0 (batch boundary, no wait).

#define BB 2
#define SS 2048
#define DDIM 128
#define NDIM 2048
#define TT (BB*SS)        // 4096 tokens
#define NTILE (TT/16)     // 256 t-tiles

typedef short short8 __attribute__((ext_vector_type(8)));
typedef float floatx4 __attribute__((ext_vector_type(4)));

__device__ __forceinline__ unsigned short f2b(float f){
  unsigned u = __float_as_uint(f);
  u += 0x7FFFu + ((u >> 16) & 1u);
  return (unsigned short)(u >> 16);
}
__device__ __forceinline__ float softplus_f(float v){
  return v > 15.f ? v : __logf(1.f + __expf(v));
}
__device__ __forceinline__ void pack8(const float* __restrict__ s,
                                      unsigned short* __restrict__ d){
  floatx4 v0 = *(const floatx4*)s;
  floatx4 v1 = *(const floatx4*)(s + 4);
  short8 r;
  r[0]=(short)f2b(v0[0]); r[1]=(short)f2b(v0[1]); r[2]=(short)f2b(v0[2]); r[3]=(short)f2b(v0[3]);
  r[4]=(short)f2b(v1[0]); r[5]=(short)f2b(v1[1]); r[6]=(short)f2b(v1[2]); r[7]=(short)f2b(v1[3]);
  *(short8*)d = r;
}

// ---------------- 1. prep ----------------
__global__ void prep_kernel(const float* __restrict__ x,
                            const float* __restrict__ W_B,
                            const float* __restrict__ W_C,
                            const float* __restrict__ W_dt,
                            const float* __restrict__ A_log,
                            const float* __restrict__ W_out,
                            unsigned short* __restrict__ xp,
                            unsigned short* __restrict__ Wp3,
                            unsigned short* __restrict__ Wop,
                            float* __restrict__ Aval,
                            unsigned long long* __restrict__ Sbuf){
  const int gid = blockIdx.x * blockDim.x + threadIdx.x;   // 0..98303
  if (gid < 65536) Sbuf[gid] = 0ull;              // clear tags (1024 x 32 x 2)
  if (gid < 2048) Aval[gid] = -__expf(A_log[gid]);
  if (gid < 65536){                               // x: 256 t-tiles, K=128
    int g = gid, tile = g >> 8, kk = (g >> 6) & 3, lane = g & 63;
    int q = lane >> 4, m = lane & 15;
    pack8(x + (size_t)(tile*16 + m)*DDIM + kk*32 + q*8, xp + (size_t)g*8);
  }
  if (gid < 98304){                               // W_B/W_dt/W_C: 128 n-tiles each
    int mat = gid >> 15, g = gid & 32767;
    const float* W = (mat == 0) ? W_B : (mat == 1 ? W_dt : W_C);
    int tile = g >> 8, kk = (g >> 6) & 3, lane = g & 63;
    int q = lane >> 4, m = lane & 15;
    pack8(W + (size_t)(tile*16 + m)*DDIM + kk*32 + q*8,
          Wp3 + (size_t)mat*262144 + (size_t)g*8);
  }
  if (gid < 32768){                               // W_out: 8 d-tiles, K=2048
    int g = gid, tile = g >> 12, kk = (g >> 6) & 63, lane = g & 63;
    int q = lane >> 4, m = lane & 15;
    pack8(W_out + (size_t)(tile*16 + m)*NDIM + kk*32 + q*8, Wop + (size_t)g*8);
  }
}

// ---------------- 2. projscan with decoupled lookback ----------------
// grid (16, 64), block 256. bx = t-chunk (16 tiles), by = 32-n slice.
// Wave wv handles tiles bx*16 + wv*4 .. +4. bx%8==0 starts a batch (h=0).
// (256,2): VGPR budget 256 -> compiler's natural ~88-130, NO spill (R10
// lesson: (256,4) forced 64 VGPR -> 200MB scratch traffic -> memory-bound).
__global__ __launch_bounds__(256, 2) void projscan_kernel(
    const unsigned short* __restrict__ xp,
    const unsigned short* __restrict__ Wp3,
    const float* __restrict__ b_B,
    const float* __restrict__ b_dt,
    const float* __restrict__ b_C,
    const float* __restrict__ Aval,
    unsigned long long* __restrict__ Sbuf,   // [64*16][32][2] tagged local (P,H)
    unsigned short* __restrict__ ybp){
  __shared__ unsigned short sW[3*4096];      // 24 KB packed weights (this n-slice)
  __shared__ unsigned short sYT[4][16*40];   // per-wave transpose tile
  __shared__ float sPw[4][32], sHw[4][32];   // per-wave chain totals
  __shared__ float sIw[4][32];               // per-wave init states
  const int tid  = threadIdx.x;
  const int lane = tid & 63;
  const int wv   = tid >> 6;
  const int m    = lane & 15;
  const int q    = lane >> 4;
  const int bx   = blockIdx.x;
  const int by   = blockIdx.y;               // chain id
  const int n0   = by*32;

  // stage packed weights: 3 mats x 2 n-tiles x 2048 ushort
  for (int i = tid; i < 1536; i += 256){
    int mat = i >> 9, rem = i & 511;
    *(short8*)(sW + mat*4096 + rem*8) =
        *(const short8*)(Wp3 + (size_t)mat*262144 + (size_t)by*4096 + rem*8);
  }
  __syncthreads();

  // per-nt biases (n = n0 + nt*16 + m)
  float bBv[2], bDv[2], bCv[2], Avv[2];
#pragma unroll
  for (int nt = 0; nt < 2; ++nt){
    const int n = n0 + nt*16 + m;
    bBv[nt] = b_B[n]; bDv[nt] = b_dt[n]; bCv[nt] = b_C[n]; Avv[nt] = Aval[n];
  }

  // ---- Phase A: 4 sequential tiles, local scan (init 0), keep y/coef packed
  unsigned ypk[4][2][2], cpk[4][2][2];
  float pe_t[4][2], he_t[4][2];
  float pa_run[2] = {1.f, 1.f}, ha_run[2] = {0.f, 0.f};

#pragma unroll
  for (int i = 0; i < 4; ++i){
    const int tile = bx*16 + wv*4 + i;
    short8 xf[4];
#pragma unroll
    for (int kk = 0; kk < 4; ++kk)
      xf[kk] = *(const short8*)(xp + (size_t)tile*2048 + kk*512 + lane*8);

    floatx4 acc[3][2];
#pragma unroll
    for (int mat = 0; mat < 3; ++mat)
#pragma unroll
      for (int nt = 0; nt < 2; ++nt)
        acc[mat][nt] = (floatx4){0.f,0.f,0.f,0.f};
#pragma unroll
    for (int nt = 0; nt < 2; ++nt)
#pragma unroll
      for (int kk = 0; kk < 4; ++kk){
        short8 wB = *(const short8*)(sW +         nt*2048 + kk*512 + lane*8);
        short8 wD = *(const short8*)(sW + 4096 +  nt*2048 + kk*512 + lane*8);
        short8 wC = *(const short8*)(sW + 8192 +  nt*2048 + kk*512 + lane*8);
        acc[0][nt] = __builtin_amdgcn_mfma_f32_16x16x32_bf16(xf[kk], wB, acc[0][nt], 0, 0, 0);
        acc[1][nt] = __builtin_amdgcn_mfma_f32_16x16x32_bf16(xf[kk], wD, acc[1][nt], 0, 0, 0);
        acc[2][nt] = __builtin_amdgcn_mfma_f32_16x16x32_bf16(xf[kk], wC, acc[2][nt], 0, 0, 0);
      }

#pragma unroll
    for (int nt = 0; nt < 2; ++nt){
      float Ar[4], Br[4], Cc[4];
#pragma unroll
      for (int r = 0; r < 4; ++r){
        float dtv = softplus_f(acc[1][nt][r] + bDv[nt]);
        Ar[r] = __expf(dtv * Avv[nt]);
        Br[r] = dtv * (acc[0][nt][r] + bBv[nt]);
        Cc[r] = acc[2][nt][r] + bCv[nt];
      }
      // compose lane's 4-token segment
      float P = Ar[0], H = Br[0];
#pragma unroll
      for (int r = 1; r < 4; ++r){ H = Ar[r]*H + Br[r]; P *= Ar[r]; }
      // inclusive scan across q (2 steps)
      float pp = __shfl(P, (lane - 16) & 63, 64);
      float hh = __shfl(H, (lane - 16) & 63, 64);
      if (q >= 1){ H = P*hh + H; P *= pp; }
      pp = __shfl(P, (lane - 32) & 63, 64);
      hh = __shfl(H, (lane - 32) & 63, 64);
      if (q >= 2){ H = P*hh + H; P *= pp; }
      // exclusive prefix for this q
      float pe = __shfl(P, (lane - 16) & 63, 64);
      float he = __shfl(H, (lane - 16) & 63, 64);
      if (q == 0){ pe = 1.f; he = 0.f; }
      // tile totals broadcast (q==3 inclusive)
      float pb = __shfl(P, m + 48, 64);
      float hb = __shfl(H, m + 48, 64);

      float h = he, pa = pe;
      unsigned short yr[4], cr[4];
#pragma unroll
      for (int r = 0; r < 4; ++r){
        h = Ar[r]*h + Br[r];
        pa *= Ar[r];
        yr[r] = f2b(Cc[r]*h);
        cr[r] = f2b(Cc[r]*pa);
      }
      ypk[i][nt][0] = (unsigned)yr[0] | ((unsigned)yr[1] << 16);
      ypk[i][nt][1] = (unsigned)yr[2] | ((unsigned)yr[3] << 16);
      cpk[i][nt][0] = (unsigned)cr[0] | ((unsigned)cr[1] << 16);
      cpk[i][nt][1] = (unsigned)cr[2] | ((unsigned)cr[3] << 16);

      pe_t[i][nt] = pa_run[nt];
      he_t[i][nt] = ha_run[nt];
      ha_run[nt] = pb*ha_run[nt] + hb;
      pa_run[nt] *= pb;
    }
  }
  // publish wave totals per n (identical across q; q==0 writes)
  if (q == 0){
#pragma unroll
    for (int nt = 0; nt < 2; ++nt){
      sPw[wv][nt*16 + m] = pa_run[nt];
      sHw[wv][nt*16 + m] = ha_run[nt];
    }
  }
  __syncthreads();

  // ---- Phase B: publish LOCAL aggregate, decoupled lookback (threads 0..31)
  if (tid < 32){
    float Pw[4], Hw[4];
#pragma unroll
    for (int w2 = 0; w2 < 4; ++w2){ Pw[w2] = sPw[w2][tid]; Hw[w2] = sHw[w2][tid]; }
    // block-local aggregate over the 4 waves
    float pb = 1.f, hb = 0.f;
#pragma unroll
    for (int w2 = 0; w2 < 4; ++w2){ hb = Pw[w2]*hb + Hw[w2]; pb *= Pw[w2]; }
    // publish immediately — successors don't wait on OUR predecessors
    unsigned long long* dst = Sbuf + ((size_t)(by*16 + bx)*32 + tid)*2;
    __hip_atomic_store(dst,   (1ull << 32) | (unsigned long long)__float_as_uint(pb),
                       __ATOMIC_RELAXED, __HIP_MEMORY_SCOPE_AGENT);
    __hip_atomic_store(dst+1, (1ull << 32) | (unsigned long long)__float_as_uint(hb),
                       __ATOMIC_RELAXED, __HIP_MEMORY_SCOPE_AGENT);
    // gather ALL predecessors' locals concurrently (retry-mask, one LLC RTT)
    float S = 0.f;
    const int cnt = bx & 7;                // # predecessors within batch row
    if (cnt){
      const int j0 = bx & ~7;
      unsigned long long vp0=0,vp1=0,vp2=0,vp3=0,vp4=0,vp5=0,vp6=0;
      unsigned long long vh0=0,vh1=0,vh2=0,vh3=0,vh4=0,vh5=0,vh6=0;
      unsigned got = 0;
      const unsigned all = (1u << cnt) - 1u;
      const unsigned long long* base = Sbuf + ((size_t)(by*16 + j0)*32 + tid)*2;
      for (;;){
#define LOOKBACK(J, VP, VH)                                                     \
        if (J < cnt && !(got & (1u << J))){                                     \
          unsigned long long a = __hip_atomic_load(base + (size_t)J*64,         \
              __ATOMIC_RELAXED, __HIP_MEMORY_SCOPE_AGENT);                      \
          unsigned long long b = __hip_atomic_load(base + (size_t)J*64 + 1,     \
              __ATOMIC_RELAXED, __HIP_MEMORY_SCOPE_AGENT);                      \
          if (((unsigned)(a >> 32) & (unsigned)(b >> 32)) == 1u){               \
            VP = a; VH = b; got |= 1u << J;                                     \
          }                                                                     \
        }
        LOOKBACK(0, vp0, vh0) LOOKBACK(1, vp1, vh1) LOOKBACK(2, vp2, vh2)
        LOOKBACK(3, vp3, vh3) LOOKBACK(4, vp4, vh4) LOOKBACK(5, vp5, vh5)
        LOOKBACK(6, vp6, vh6)
#undef LOOKBACK
        if (got == all) break;
        __builtin_amdgcn_s_sleep(1);
      }
      // ordered composition j0..bx-1: S = P_j*S + H_j
#define COMPOSE(J, VP, VH)                                                      \
      if (J < cnt) S = __uint_as_float((unsigned)VP)*S + __uint_as_float((unsigned)VH);
      COMPOSE(0, vp0, vh0) COMPOSE(1, vp1, vh1) COMPOSE(2, vp2, vh2)
      COMPOSE(3, vp3, vh3) COMPOSE(4, vp4, vh4) COMPOSE(5, vp5, vh5)
      COMPOSE(6, vp6, vh6)
#undef COMPOSE
    }
    // per-wave init states
    float s = S;
#pragma unroll
    for (int w2 = 0; w2 < 4; ++w2){
      sIw[w2][tid] = s;
      s = Pw[w2]*s + Hw[w2];
    }
  }
  __syncthreads();

  // ---- Phase C: fixup + transpose + store
  float iw[2];
#pragma unroll
  for (int nt = 0; nt < 2; ++nt) iw[nt] = sIw[wv][nt*16 + m];
#pragma unroll
  for (int i = 0; i < 4; ++i){
    const int tile = bx*16 + wv*4 + i;
#pragma unroll
    for (int nt = 0; nt < 2; ++nt){
      float it = pe_t[i][nt]*iw[nt] + he_t[i][nt];
#pragma unroll
      for (int j = 0; j < 2; ++j){
        unsigned yp = ypk[i][nt][j], cp = cpk[i][nt][j];
        float y0 = __uint_as_float(yp << 16);
        float y1 = __uint_as_float(yp & 0xffff0000u);
        float c0 = __uint_as_float(cp << 16);
        float c1 = __uint_as_float(cp & 0xffff0000u);
        sYT[wv][(q*4 + j*2 + 0)*40 + nt*16 + m] = f2b(y0 + c0*it);
        sYT[wv][(q*4 + j*2 + 1)*40 + nt*16 + m] = f2b(y1 + c1*it);
      }
    }
    short8 yv = *(const short8*)&sYT[wv][m*40 + q*8];
    *(short8*)(ybp + (size_t)tile*32768 + (size_t)by*512 + (size_t)lane*8) = yv;
  }
}

// ---------------- 3. output projection ----------------
// grid NTILE=256, block 256. Wave wv: kk in [wv*16, wv*16+16), all 8 d-tiles.
__global__ void outproj_kernel(const unsigned short* __restrict__ ybp,
                               const unsigned short* __restrict__ Wop,
                               const float* __restrict__ b_out,
                               float* __restrict__ out){
  __shared__ float red[4*2048];
  const int tid  = threadIdx.x;
  const int lane = tid & 63;
  const int wv   = tid >> 6;
  const int m    = lane & 15;
  const int q    = lane >> 4;
  const int tile = blockIdx.x;

  floatx4 acc[8];
#pragma unroll
  for (int dt = 0; dt < 8; ++dt) acc[dt] = (floatx4){0.f,0.f,0.f,0.f};

  const unsigned short* aP = ybp + (size_t)tile*32768 + lane*8;
  const unsigned short* bP = Wop + (size_t)lane*8;
#pragma unroll 4
  for (int kk = wv*16; kk < wv*16 + 16; ++kk){
    short8 af = *(const short8*)(aP + (size_t)kk*512);
#pragma unroll
    for (int dt = 0; dt < 8; ++dt){
      short8 bf = *(const short8*)(bP + (size_t)dt*32768 + (size_t)kk*512);
      acc[dt] = __builtin_amdgcn_mfma_f32_16x16x32_bf16(af, bf, acc[dt], 0, 0, 0);
    }
  }
#pragma unroll
  for (int dt = 0; dt < 8; ++dt)
#pragma unroll
    for (int r = 0; r < 4; ++r)
      red[wv*2048 + (q*4 + r)*128 + dt*16 + m] = acc[dt][r];
  __syncthreads();
#pragma unroll
  for (int i = 0; i < 8; ++i){
    int idx = i*256 + tid;                        // 0..2047 = tl*128 + d
    float s = red[idx] + red[2048 + idx] + red[4096 + idx] + red[6144 + idx];
    int tl = idx >> 7, d = idx & 127;
    out[(size_t)(tile*16 + tl)*DDIM + d] = s + b_out[d];
  }
}

extern "C" void kernel_launch(void* const* d_in, const int* in_sizes, int n_in,
                              void* d_out, int out_size, void* d_ws, size_t ws_size,
                              hipStream_t stream) {
  const float* x     = (const float*)d_in[0];
  const float* W_B   = (const float*)d_in[1];
  const float* b_B   = (const float*)d_in[2];
  const float* W_C   = (const float*)d_in[3];
  const float* b_C   = (const float*)d_in[4];
  const float* W_dt  = (const float*)d_in[5];
  const float* b_dt  = (const float*)d_in[6];
  const float* A_log = (const float*)d_in[7];
  const float* W_out = (const float*)d_in[8];
  const float* b_out = (const float*)d_in[9];
  float* out = (float*)d_out;

  char* w = (char*)d_ws;
  unsigned short* xp    = (unsigned short*)(w + 0x0000000);  // 1 MB
  unsigned short* Wp3   = (unsigned short*)(w + 0x0100000);  // 1.5 MB
  unsigned short* Wop   = (unsigned short*)(w + 0x0280000);  // 0.5 MB
  float*          Aval  = (float*)         (w + 0x0300000);  // 8 KB
  unsigned short* ybp   = (unsigned short*)(w + 0x0310000);  // 16 MB
  unsigned long long* Sbuf = (unsigned long long*)(w + 0x1310000); // 512 KB
  // total ~19.9 MB

  prep_kernel<<<384, 256, 0, stream>>>(
      x, W_B, W_C, W_dt, A_log, W_out, xp, Wp3, Wop, Aval, Sbuf);

  projscan_kernel<<<dim3(16, 64), 256, 0, stream>>>(
      xp, Wp3, b_B, b_dt, b_C, Aval, Sbuf, ybp);

  outproj_kernel<<<NTILE, 256, 0, stream>>>(ybp, Wop, b_out, out);
}

// Round 3
// 115.527 us; speedup vs baseline: 1.2176x; 1.0182x over previous
//
#include <hip/hip_runtime.h>

// Rec1_43748536877661 — diagonal SSM block, MI355X gfx950.
// B=2,S=2048,D=128,N=2048. fp32 in/out, bf16 MFMA compute (tol 2.14e-2).
// R12: R11 + XCD-LOCAL CHAIN ROWS + single-word publish.
// R11 post-mortem: decoupled lookback bought only ~2us (projscan ~43us);
// issue-work is ~10us, so ~33us is stall = row-mate skew + Sbuf poll RTT.
// Grid (16,64) linear id round-robins XCDs (id%8), so chain row-mates sat
// on DIFFERENT XCDs -> every Sbuf poll was a cross-XCD LLC miss (~900cy)
// and row skew was uncorrelated-scheduler max-of-7. Now block ids are
// swizzled so all 8 row-mates share id%8 -> one XCD -> Sbuf line lives in
// that XCD's L2 (~200cy) and row-mates co-schedule. Deadlock safety: waiter
// at row position j targets positions <j whose swizzled linear ids are
// strictly smaller (dispatched earlier) -> holds for ANY id->XCD mapping.
// Publish is one 64-bit word [P_bits|H_bits]; validity = P_bits!=0
// (P=prod exp(dt*A)>0; clamped >=1e-30 so it never underflows to 0).
//  1. prep      pack x,W_B/dt/C,W_out fragment-linear bf16; Aval; zero Sbuf
//  2. projscan  grid(16,64): 16 t-tiles x 32 n per block; GEMM+scan local,
//               publish local agg, decoupled lookback, fixup -> y (bf16 A-frag)
//  3. outproj   y @ W_out^T + b_out -> fp32 out

#define BB 2
#define SS 2048
#define DDIM 128
#define NDIM 2048
#define TT (BB*SS)        // 4096 tokens
#define NTILE (TT/16)     // 256 t-tiles

typedef short short8 __attribute__((ext_vector_type(8)));
typedef float floatx4 __attribute__((ext_vector_type(4)));

__device__ __forceinline__ unsigned short f2b(float f){
  unsigned u = __float_as_uint(f);
  u += 0x7FFFu + ((u >> 16) & 1u);
  return (unsigned short)(u >> 16);
}
__device__ __forceinline__ float softplus_f(float v){
  return v > 15.f ? v : __logf(1.f + __expf(v));
}
__device__ __forceinline__ void pack8(const float* __restrict__ s,
                                      unsigned short* __restrict__ d){
  floatx4 v0 = *(const floatx4*)s;
  floatx4 v1 = *(const floatx4*)(s + 4);
  short8 r;
  r[0]=(short)f2b(v0[0]); r[1]=(short)f2b(v0[1]); r[2]=(short)f2b(v0[2]); r[3]=(short)f2b(v0[3]);
  r[4]=(short)f2b(v1[0]); r[5]=(short)f2b(v1[1]); r[6]=(short)f2b(v1[2]); r[7]=(short)f2b(v1[3]);
  *(short8*)d = r;
}

// ---------------- 1. prep ----------------
__global__ void prep_kernel(const float* __restrict__ x,
                            const float* __restrict__ W_B,
                            const float* __restrict__ W_C,
                            const float* __restrict__ W_dt,
                            const float* __restrict__ A_log,
                            const float* __restrict__ W_out,
                            unsigned short* __restrict__ xp,
                            unsigned short* __restrict__ Wp3,
                            unsigned short* __restrict__ Wop,
                            float* __restrict__ Aval,
                            unsigned long long* __restrict__ Sbuf){
  const int gid = blockIdx.x * blockDim.x + threadIdx.x;   // 0..98303
  if (gid < 32768) Sbuf[gid] = 0ull;              // clear (1024 entries x 32 n)
  if (gid < 2048) Aval[gid] = -__expf(A_log[gid]);
  if (gid < 65536){                               // x: 256 t-tiles, K=128
    int g = gid, tile = g >> 8, kk = (g >> 6) & 3, lane = g & 63;
    int q = lane >> 4, m = lane & 15;
    pack8(x + (size_t)(tile*16 + m)*DDIM + kk*32 + q*8, xp + (size_t)g*8);
  }
  if (gid < 98304){                               // W_B/W_dt/W_C: 128 n-tiles each
    int mat = gid >> 15, g = gid & 32767;
    const float* W = (mat == 0) ? W_B : (mat == 1 ? W_dt : W_C);
    int tile = g >> 8, kk = (g >> 6) & 3, lane = g & 63;
    int q = lane >> 4, m = lane & 15;
    pack8(W + (size_t)(tile*16 + m)*DDIM + kk*32 + q*8,
          Wp3 + (size_t)mat*262144 + (size_t)g*8);
  }
  if (gid < 32768){                               // W_out: 8 d-tiles, K=2048
    int g = gid, tile = g >> 12, kk = (g >> 6) & 63, lane = g & 63;
    int q = lane >> 4, m = lane & 15;
    pack8(W_out + (size_t)(tile*16 + m)*NDIM + kk*32 + q*8, Wop + (size_t)g*8);
  }
}

// ---------------- 2. projscan, XCD-local decoupled lookback ----------------
// grid (16, 64), block 256. Physical id p = by*16+bx is swizzled:
//   xcd=p&7, slot=p>>3, rr=slot&15, j=slot>>4, row=xcd*16+rr
//   by=row>>1, bx=(row&1)*8+j   (j = position within the 8-block chain row)
// All 8 row-mates share p%8 -> same XCD (if mapping is id%8; else still safe).
// (256,2): VGPR budget 256 -> natural ~88, NO spill (R10 lesson).
__global__ __launch_bounds__(256, 2) void projscan_kernel(
    const unsigned short* __restrict__ xp,
    const unsigned short* __restrict__ Wp3,
    const float* __restrict__ b_B,
    const float* __restrict__ b_dt,
    const float* __restrict__ b_C,
    const float* __restrict__ Aval,
    unsigned long long* __restrict__ Sbuf,   // [64*16][32] packed (P|H)
    unsigned short* __restrict__ ybp){
  __shared__ unsigned short sW[3*4096];      // 24 KB packed weights (this n-slice)
  __shared__ unsigned short sYT[4][16*40];   // per-wave transpose tile
  __shared__ float sPw[4][32], sHw[4][32];   // per-wave chain totals
  __shared__ float sIw[4][32];               // per-wave init states
  const int tid  = threadIdx.x;
  const int lane = tid & 63;
  const int wv   = tid >> 6;
  const int m    = lane & 15;
  const int q    = lane >> 4;
  // --- XCD-local row swizzle ---
  const int p    = blockIdx.y * 16 + blockIdx.x;  // dispatch-linear id
  const int xcd  = p & 7;
  const int slot = p >> 3;                        // 0..127
  const int rr   = slot & 15;
  const int j    = slot >> 4;                     // 0..7 position in row
  const int row  = xcd*16 + rr;                   // 0..127
  const int by   = row >> 1;                      // n-slice 0..63
  const int bx   = (row & 1)*8 + j;               // t-chunk 0..15
  const int n0   = by*32;

  // stage packed weights: 3 mats x 2 n-tiles x 2048 ushort
  for (int i = tid; i < 1536; i += 256){
    int mat = i >> 9, rem = i & 511;
    *(short8*)(sW + mat*4096 + rem*8) =
        *(const short8*)(Wp3 + (size_t)mat*262144 + (size_t)by*4096 + rem*8);
  }
  __syncthreads();

  // per-nt biases (n = n0 + nt*16 + m)
  float bBv[2], bDv[2], bCv[2], Avv[2];
#pragma unroll
  for (int nt = 0; nt < 2; ++nt){
    const int n = n0 + nt*16 + m;
    bBv[nt] = b_B[n]; bDv[nt] = b_dt[n]; bCv[nt] = b_C[n]; Avv[nt] = Aval[n];
  }

  // ---- Phase A: 4 sequential tiles, local scan (init 0), keep y/coef packed
  unsigned ypk[4][2][2], cpk[4][2][2];
  float pe_t[4][2], he_t[4][2];
  float pa_run[2] = {1.f, 1.f}, ha_run[2] = {0.f, 0.f};

#pragma unroll
  for (int i = 0; i < 4; ++i){
    const int tile = bx*16 + wv*4 + i;
    short8 xf[4];
#pragma unroll
    for (int kk = 0; kk < 4; ++kk)
      xf[kk] = *(const short8*)(xp + (size_t)tile*2048 + kk*512 + lane*8);

    floatx4 acc[3][2];
#pragma unroll
    for (int mat = 0; mat < 3; ++mat)
#pragma unroll
      for (int nt = 0; nt < 2; ++nt)
        acc[mat][nt] = (floatx4){0.f,0.f,0.f,0.f};
#pragma unroll
    for (int nt = 0; nt < 2; ++nt)
#pragma unroll
      for (int kk = 0; kk < 4; ++kk){
        short8 wB = *(const short8*)(sW +         nt*2048 + kk*512 + lane*8);
        short8 wD = *(const short8*)(sW + 4096 +  nt*2048 + kk*512 + lane*8);
        short8 wC = *(const short8*)(sW + 8192 +  nt*2048 + kk*512 + lane*8);
        acc[0][nt] = __builtin_amdgcn_mfma_f32_16x16x32_bf16(xf[kk], wB, acc[0][nt], 0, 0, 0);
        acc[1][nt] = __builtin_amdgcn_mfma_f32_16x16x32_bf16(xf[kk], wD, acc[1][nt], 0, 0, 0);
        acc[2][nt] = __builtin_amdgcn_mfma_f32_16x16x32_bf16(xf[kk], wC, acc[2][nt], 0, 0, 0);
      }

#pragma unroll
    for (int nt = 0; nt < 2; ++nt){
      float Ar[4], Br[4], Cc[4];
#pragma unroll
      for (int r = 0; r < 4; ++r){
        float dtv = softplus_f(acc[1][nt][r] + bDv[nt]);
        Ar[r] = __expf(dtv * Avv[nt]);
        Br[r] = dtv * (acc[0][nt][r] + bBv[nt]);
        Cc[r] = acc[2][nt][r] + bCv[nt];
      }
      // compose lane's 4-token segment
      float P = Ar[0], H = Br[0];
#pragma unroll
      for (int r = 1; r < 4; ++r){ H = Ar[r]*H + Br[r]; P *= Ar[r]; }
      // inclusive scan across q (2 steps)
      float pp = __shfl(P, (lane - 16) & 63, 64);
      float hh = __shfl(H, (lane - 16) & 63, 64);
      if (q >= 1){ H = P*hh + H; P *= pp; }
      pp = __shfl(P, (lane - 32) & 63, 64);
      hh = __shfl(H, (lane - 32) & 63, 64);
      if (q >= 2){ H = P*hh + H; P *= pp; }
      // exclusive prefix for this q
      float pe = __shfl(P, (lane - 16) & 63, 64);
      float he = __shfl(H, (lane - 16) & 63, 64);
      if (q == 0){ pe = 1.f; he = 0.f; }
      // tile totals broadcast (q==3 inclusive)
      float pb = __shfl(P, m + 48, 64);
      float hb = __shfl(H, m + 48, 64);

      float h = he, pa = pe;
      unsigned short yr[4], cr[4];
#pragma unroll
      for (int r = 0; r < 4; ++r){
        h = Ar[r]*h + Br[r];
        pa *= Ar[r];
        yr[r] = f2b(Cc[r]*h);
        cr[r] = f2b(Cc[r]*pa);
      }
      ypk[i][nt][0] = (unsigned)yr[0] | ((unsigned)yr[1] << 16);
      ypk[i][nt][1] = (unsigned)yr[2] | ((unsigned)yr[3] << 16);
      cpk[i][nt][0] = (unsigned)cr[0] | ((unsigned)cr[1] << 16);
      cpk[i][nt][1] = (unsigned)cr[2] | ((unsigned)cr[3] << 16);

      pe_t[i][nt] = pa_run[nt];
      he_t[i][nt] = ha_run[nt];
      ha_run[nt] = pb*ha_run[nt] + hb;
      pa_run[nt] *= pb;
    }
  }
  // publish wave totals per n (identical across q; q==0 writes)
  if (q == 0){
#pragma unroll
    for (int nt = 0; nt < 2; ++nt){
      sPw[wv][nt*16 + m] = pa_run[nt];
      sHw[wv][nt*16 + m] = ha_run[nt];
    }
  }
  __syncthreads();

  // ---- Phase B: publish LOCAL aggregate, decoupled lookback (threads 0..31)
  if (tid < 32){
    float Pw[4], Hw[4];
#pragma unroll
    for (int w2 = 0; w2 < 4; ++w2){ Pw[w2] = sPw[w2][tid]; Hw[w2] = sHw[w2][tid]; }
    // block-local aggregate over the 4 waves
    float pb = 1.f, hb = 0.f;
#pragma unroll
    for (int w2 = 0; w2 < 4; ++w2){ hb = Pw[w2]*hb + Hw[w2]; pb *= Pw[w2]; }
    // single-word publish: [P|H]; validity = P bits != 0 (P>0, clamped)
    float pbc = fmaxf(pb, 1e-30f);
    __hip_atomic_store(Sbuf + (size_t)(by*16 + bx)*32 + tid,
        ((unsigned long long)__float_as_uint(pbc) << 32) |
         (unsigned long long)__float_as_uint(hb),
        __ATOMIC_RELAXED, __HIP_MEMORY_SCOPE_AGENT);
    // gather ALL predecessors' locals concurrently (retry-mask, one L2 RTT)
    float S = 0.f;
    const int cnt = bx & 7;                // # predecessors within batch row
    if (cnt){
      const int j0 = bx & ~7;
      unsigned long long v0=0,v1=0,v2=0,v3=0,v4=0,v5=0,v6=0;
      unsigned got = 0;
      const unsigned all = (1u << cnt) - 1u;
      const unsigned long long* base = Sbuf + (size_t)(by*16 + j0)*32 + tid;
      for (;;){
#define LOOKBACK(J, V)                                                          \
        if (J < cnt && !(got & (1u << J))){                                     \
          unsigned long long a = __hip_atomic_load(base + (size_t)J*32,         \
              __ATOMIC_RELAXED, __HIP_MEMORY_SCOPE_AGENT);                      \
          if ((unsigned)(a >> 32) != 0u){ V = a; got |= 1u << J; }              \
        }
        LOOKBACK(0, v0) LOOKBACK(1, v1) LOOKBACK(2, v2) LOOKBACK(3, v3)
        LOOKBACK(4, v4) LOOKBACK(5, v5) LOOKBACK(6, v6)
#undef LOOKBACK
        if (got == all) break;
        __builtin_amdgcn_s_sleep(1);
      }
      // ordered composition j0..bx-1: S = P_j*S + H_j
#define COMPOSE(J, V)                                                           \
      if (J < cnt) S = __uint_as_float((unsigned)(V >> 32))*S +                 \
                       __uint_as_float((unsigned)V);
      COMPOSE(0, v0) COMPOSE(1, v1) COMPOSE(2, v2) COMPOSE(3, v3)
      COMPOSE(4, v4) COMPOSE(5, v5) COMPOSE(6, v6)
#undef COMPOSE
    }
    // per-wave init states
    float s = S;
#pragma unroll
    for (int w2 = 0; w2 < 4; ++w2){
      sIw[w2][tid] = s;
      s = Pw[w2]*s + Hw[w2];
    }
  }
  __syncthreads();

  // ---- Phase C: fixup + transpose + store
  float iw[2];
#pragma unroll
  for (int nt = 0; nt < 2; ++nt) iw[nt] = sIw[wv][nt*16 + m];
#pragma unroll
  for (int i = 0; i < 4; ++i){
    const int tile = bx*16 + wv*4 + i;
#pragma unroll
    for (int nt = 0; nt < 2; ++nt){
      float it = pe_t[i][nt]*iw[nt] + he_t[i][nt];
#pragma unroll
      for (int j2 = 0; j2 < 2; ++j2){
        unsigned yp = ypk[i][nt][j2], cp = cpk[i][nt][j2];
        float y0 = __uint_as_float(yp << 16);
        float y1 = __uint_as_float(yp & 0xffff0000u);
        float c0 = __uint_as_float(cp << 16);
        float c1 = __uint_as_float(cp & 0xffff0000u);
        sYT[wv][(q*4 + j2*2 + 0)*40 + nt*16 + m] = f2b(y0 + c0*it);
        sYT[wv][(q*4 + j2*2 + 1)*40 + nt*16 + m] = f2b(y1 + c1*it);
      }
    }
    short8 yv = *(const short8*)&sYT[wv][m*40 + q*8];
    *(short8*)(ybp + (size_t)tile*32768 + (size_t)by*512 + (size_t)lane*8) = yv;
  }
}

// ---------------- 3. output projection ----------------
// grid NTILE=256, block 256. Wave wv: kk in [wv*16, wv*16+16), all 8 d-tiles.
__global__ void outproj_kernel(const unsigned short* __restrict__ ybp,
                               const unsigned short* __restrict__ Wop,
                               const float* __restrict__ b_out,
                               float* __restrict__ out){
  __shared__ float red[4*2048];
  const int tid  = threadIdx.x;
  const int lane = tid & 63;
  const int wv   = tid >> 6;
  const int m    = lane & 15;
  const int q    = lane >> 4;
  const int tile = blockIdx.x;

  floatx4 acc[8];
#pragma unroll
  for (int dt = 0; dt < 8; ++dt) acc[dt] = (floatx4){0.f,0.f,0.f,0.f};

  const unsigned short* aP = ybp + (size_t)tile*32768 + lane*8;
  const unsigned short* bP = Wop + (size_t)lane*8;
#pragma unroll 4
  for (int kk = wv*16; kk < wv*16 + 16; ++kk){
    short8 af = *(const short8*)(aP + (size_t)kk*512);
#pragma unroll
    for (int dt = 0; dt < 8; ++dt){
      short8 bf = *(const short8*)(bP + (size_t)dt*32768 + (size_t)kk*512);
      acc[dt] = __builtin_amdgcn_mfma_f32_16x16x32_bf16(af, bf, acc[dt], 0, 0, 0);
    }
  }
#pragma unroll
  for (int dt = 0; dt < 8; ++dt)
#pragma unroll
    for (int r = 0; r < 4; ++r)
      red[wv*2048 + (q*4 + r)*128 + dt*16 + m] = acc[dt][r];
  __syncthreads();
#pragma unroll
  for (int i = 0; i < 8; ++i){
    int idx = i*256 + tid;                        // 0..2047 = tl*128 + d
    float s = red[idx] + red[2048 + idx] + red[4096 + idx] + red[6144 + idx];
    int tl = idx >> 7, d = idx & 127;
    out[(size_t)(tile*16 + tl)*DDIM + d] = s + b_out[d];
  }
}

extern "C" void kernel_launch(void* const* d_in, const int* in_sizes, int n_in,
                              void* d_out, int out_size, void* d_ws, size_t ws_size,
                              hipStream_t stream) {
  const float* x     = (const float*)d_in[0];
  const float* W_B   = (const float*)d_in[1];
  const float* b_B   = (const float*)d_in[2];
  const float* W_C   = (const float*)d_in[3];
  const float* b_C   = (const float*)d_in[4];
  const float* W_dt  = (const float*)d_in[5];
  const float* b_dt  = (const float*)d_in[6];
  const float* A_log = (const float*)d_in[7];
  const float* W_out = (const float*)d_in[8];
  const float* b_out = (const float*)d_in[9];
  float* out = (float*)d_out;

  char* w = (char*)d_ws;
  unsigned short* xp    = (unsigned short*)(w + 0x0000000);  // 1 MB
  unsigned short* Wp3   = (unsigned short*)(w + 0x0100000);  // 1.5 MB
  unsigned short* Wop   = (unsigned short*)(w + 0x0280000);  // 0.5 MB
  float*          Aval  = (float*)         (w + 0x0300000);  // 8 KB
  unsigned short* ybp   = (unsigned short*)(w + 0x0310000);  // 16 MB
  unsigned long long* Sbuf = (unsigned long long*)(w + 0x1310000); // 256 KB
  // total ~19.7 MB

  prep_kernel<<<384, 256, 0, stream>>>(
      x, W_B, W_C, W_dt, A_log, W_out, xp, Wp3, Wop, Aval, Sbuf);

  projscan_kernel<<<dim3(16, 64), 256, 0, stream>>>(
      xp, Wp3, b_B, b_dt, b_C, Aval, Sbuf, ybp);

  outproj_kernel<<<NTILE, 256, 0, stream>>>(ybp, Wop, b_out, out);
}

// Round 4
// 115.465 us; speedup vs baseline: 1.2182x; 1.0005x over previous
//
#include <hip/hip_runtime.h>

// Rec1_43748536877661 — diagonal SSM block, MI355X gfx950.
// B=2,S=2048,D=128,N=2048. fp32 in/out, bf16 MFMA compute (tol 2.14e-2).
// R13: R12 + poll-backoff + xf prefetch + cvt_pk packing + LDS alias.
// R11/R12 post-mortem: lookback restructures bought 2us each -> sync is NOT
// the wall. projscan ~41us vs ~10us VALU issue + ~3us MFMA. New theory:
// (1) 7/8 of blocks spin-poll Sbuf at s_sleep(1) (~100cy period, 7x32-lane
//     atomic loads per iter) -> L2 request flood starves workers' xp loads
//     -> Phase A drags -> more waiters -> straggler tail (R9 occupancy 17.8%
//     = mean block life ~16us in a 44us kernel). Fix: sleep ramp 2->8->32.
// (2) At 88 VGPR the compiler can't hoist next tile's xf loads over the
//     current tile's trans/shuffle scan. Fix: explicit 1-ahead prefetch
//     issued between MFMAs and scan.
// (3) v_cvt_pk_bf16_f32 packs y/coef pairs (1 inst vs ~8 manual RNE).
// (4) sYT aliases into sW (dead after Phase A barrier): LDS 31232->26112.
//  1. prep      pack x,W_B/dt/C,W_out fragment-linear bf16; Aval; zero Sbuf
//  2. projscan  grid(16,64): 16 t-tiles x 32 n per block; GEMM+scan local,
//               publish local agg, decoupled lookback, fixup -> y (bf16 A-frag)
//  3. outproj   y @ W_out^T + b_out -> fp32 out
// Deadlock safety: waiter at row position j targets positions <j whose
// swizzled linear ids are strictly smaller (dispatched earlier; publish is
// unconditional after Phase A) -> acyclic for ANY id->XCD mapping.

#define BB 2
#define SS 2048
#define DDIM 128
#define NDIM 2048
#define TT (BB*SS)        // 4096 tokens
#define NTILE (TT/16)     // 256 t-tiles

typedef short short8 __attribute__((ext_vector_type(8)));
typedef float floatx4 __attribute__((ext_vector_type(4)));

__device__ __forceinline__ unsigned short f2b(float f){
  unsigned u = __float_as_uint(f);
  u += 0x7FFFu + ((u >> 16) & 1u);
  return (unsigned short)(u >> 16);
}
__device__ __forceinline__ unsigned cvt_pk_bf16(float lo, float hi){
  unsigned r;
  asm("v_cvt_pk_bf16_f32 %0, %1, %2" : "=v"(r) : "v"(lo), "v"(hi));
  return r;
}
__device__ __forceinline__ float softplus_f(float v){
  return v > 15.f ? v : __logf(1.f + __expf(v));
}
__device__ __forceinline__ void pack8(const float* __restrict__ s,
                                      unsigned short* __restrict__ d){
  floatx4 v0 = *(const floatx4*)s;
  floatx4 v1 = *(const floatx4*)(s + 4);
  short8 r;
  r[0]=(short)f2b(v0[0]); r[1]=(short)f2b(v0[1]); r[2]=(short)f2b(v0[2]); r[3]=(short)f2b(v0[3]);
  r[4]=(short)f2b(v1[0]); r[5]=(short)f2b(v1[1]); r[6]=(short)f2b(v1[2]); r[7]=(short)f2b(v1[3]);
  *(short8*)d = r;
}

// ---------------- 1. prep ----------------
__global__ void prep_kernel(const float* __restrict__ x,
                            const float* __restrict__ W_B,
                            const float* __restrict__ W_C,
                            const float* __restrict__ W_dt,
                            const float* __restrict__ A_log,
                            const float* __restrict__ W_out,
                            unsigned short* __restrict__ xp,
                            unsigned short* __restrict__ Wp3,
                            unsigned short* __restrict__ Wop,
                            float* __restrict__ Aval,
                            unsigned long long* __restrict__ Sbuf){
  const int gid = blockIdx.x * blockDim.x + threadIdx.x;   // 0..98303
  if (gid < 32768) Sbuf[gid] = 0ull;              // clear (1024 entries x 32 n)
  if (gid < 2048) Aval[gid] = -__expf(A_log[gid]);
  if (gid < 65536){                               // x: 256 t-tiles, K=128
    int g = gid, tile = g >> 8, kk = (g >> 6) & 3, lane = g & 63;
    int q = lane >> 4, m = lane & 15;
    pack8(x + (size_t)(tile*16 + m)*DDIM + kk*32 + q*8, xp + (size_t)g*8);
  }
  if (gid < 98304){                               // W_B/W_dt/W_C: 128 n-tiles each
    int mat = gid >> 15, g = gid & 32767;
    const float* W = (mat == 0) ? W_B : (mat == 1 ? W_dt : W_C);
    int tile = g >> 8, kk = (g >> 6) & 3, lane = g & 63;
    int q = lane >> 4, m = lane & 15;
    pack8(W + (size_t)(tile*16 + m)*DDIM + kk*32 + q*8,
          Wp3 + (size_t)mat*262144 + (size_t)g*8);
  }
  if (gid < 32768){                               // W_out: 8 d-tiles, K=2048
    int g = gid, tile = g >> 12, kk = (g >> 6) & 63, lane = g & 63;
    int q = lane >> 4, m = lane & 15;
    pack8(W_out + (size_t)(tile*16 + m)*NDIM + kk*32 + q*8, Wop + (size_t)g*8);
  }
}

// ---------------- 2. projscan, XCD-local decoupled lookback ----------------
// grid (16, 64), block 256. Physical id p = by*16+bx is swizzled:
//   xcd=p&7, slot=p>>3, rr=slot&15, j=slot>>4, row=xcd*16+rr
//   by=row>>1, bx=(row&1)*8+j   (j = position within the 8-block chain row)
// (256,2): VGPR budget 256 -> natural ~88-110, NO spill (R10 lesson).
__global__ __launch_bounds__(256, 2) void projscan_kernel(
    const unsigned short* __restrict__ xp,
    const unsigned short* __restrict__ Wp3,
    const float* __restrict__ b_B,
    const float* __restrict__ b_dt,
    const float* __restrict__ b_C,
    const float* __restrict__ Aval,
    unsigned long long* __restrict__ Sbuf,   // [64*16][32] packed (P|H)
    unsigned short* __restrict__ ybp){
  __shared__ unsigned short sW[3*4096];      // 24 KB packed weights (Phase A)
  // sYT aliases the first 5 KB of sW: sW is dead after the Phase-A barrier,
  // sYT is written only after the Phase-B barrier. 4 waves x 640 ushorts.
  __shared__ float sPw[4][32], sHw[4][32];   // per-wave chain totals
  __shared__ float sIw[4][32];               // per-wave init states
  const int tid  = threadIdx.x;
  const int lane = tid & 63;
  const int wv   = tid >> 6;
  const int m    = lane & 15;
  const int q    = lane >> 4;
  // --- XCD-local row swizzle ---
  const int p    = blockIdx.y * 16 + blockIdx.x;  // dispatch-linear id
  const int xcd  = p & 7;
  const int slot = p >> 3;                        // 0..127
  const int rr   = slot & 15;
  const int j    = slot >> 4;                     // 0..7 position in row
  const int row  = xcd*16 + rr;                   // 0..127
  const int by   = row >> 1;                      // n-slice 0..63
  const int bx   = (row & 1)*8 + j;               // t-chunk 0..15
  const int n0   = by*32;
  unsigned short* sYT = sW + wv*640;              // Phase-C scratch (alias)

  // stage packed weights: 3 mats x 2 n-tiles x 2048 ushort
  for (int i = tid; i < 1536; i += 256){
    int mat = i >> 9, rem = i & 511;
    *(short8*)(sW + mat*4096 + rem*8) =
        *(const short8*)(Wp3 + (size_t)mat*262144 + (size_t)by*4096 + rem*8);
  }
  __syncthreads();

  // per-nt biases (n = n0 + nt*16 + m)
  float bBv[2], bDv[2], bCv[2], Avv[2];
#pragma unroll
  for (int nt = 0; nt < 2; ++nt){
    const int n = n0 + nt*16 + m;
    bBv[nt] = b_B[n]; bDv[nt] = b_dt[n]; bCv[nt] = b_C[n]; Avv[nt] = Aval[n];
  }

  // ---- Phase A: 4 sequential tiles, local scan (init 0), keep y/coef packed
  unsigned ypk[4][2][2], cpk[4][2][2];
  float pe_t[4][2], he_t[4][2];
  float pa_run[2] = {1.f, 1.f}, ha_run[2] = {0.f, 0.f};

  short8 xf[2][4];                           // ping-pong prefetch buffers
  {
    const int t0 = bx*16 + wv*4;
#pragma unroll
    for (int kk = 0; kk < 4; ++kk)
      xf[0][kk] = *(const short8*)(xp + (size_t)t0*2048 + kk*512 + lane*8);
  }

#pragma unroll
  for (int i = 0; i < 4; ++i){
    const int cur = i & 1;                   // constant after unroll
    floatx4 acc[3][2];
#pragma unroll
    for (int mat = 0; mat < 3; ++mat)
#pragma unroll
      for (int nt = 0; nt < 2; ++nt)
        acc[mat][nt] = (floatx4){0.f,0.f,0.f,0.f};
#pragma unroll
    for (int nt = 0; nt < 2; ++nt)
#pragma unroll
      for (int kk = 0; kk < 4; ++kk){
        short8 wB = *(const short8*)(sW +         nt*2048 + kk*512 + lane*8);
        short8 wD = *(const short8*)(sW + 4096 +  nt*2048 + kk*512 + lane*8);
        short8 wC = *(const short8*)(sW + 8192 +  nt*2048 + kk*512 + lane*8);
        acc[0][nt] = __builtin_amdgcn_mfma_f32_16x16x32_bf16(xf[cur][kk], wB, acc[0][nt], 0, 0, 0);
        acc[1][nt] = __builtin_amdgcn_mfma_f32_16x16x32_bf16(xf[cur][kk], wD, acc[1][nt], 0, 0, 0);
        acc[2][nt] = __builtin_amdgcn_mfma_f32_16x16x32_bf16(xf[cur][kk], wC, acc[2][nt], 0, 0, 0);
      }
    // prefetch next tile's x fragments NOW, so the L2 round-trip hides
    // under the scan's trans/shuffle chain below
    if (i < 3){
      const int t1 = bx*16 + wv*4 + i + 1;
#pragma unroll
      for (int kk = 0; kk < 4; ++kk)
        xf[cur^1][kk] = *(const short8*)(xp + (size_t)t1*2048 + kk*512 + lane*8);
    }

#pragma unroll
    for (int nt = 0; nt < 2; ++nt){
      float Ar[4], Br[4], Cc[4];
#pragma unroll
      for (int r = 0; r < 4; ++r){
        float dtv = softplus_f(acc[1][nt][r] + bDv[nt]);
        Ar[r] = __expf(dtv * Avv[nt]);
        Br[r] = dtv * (acc[0][nt][r] + bBv[nt]);
        Cc[r] = acc[2][nt][r] + bCv[nt];
      }
      // compose lane's 4-token segment
      float P = Ar[0], H = Br[0];
#pragma unroll
      for (int r = 1; r < 4; ++r){ H = Ar[r]*H + Br[r]; P *= Ar[r]; }
      // inclusive scan across q (2 steps)
      float pp = __shfl(P, (lane - 16) & 63, 64);
      float hh = __shfl(H, (lane - 16) & 63, 64);
      if (q >= 1){ H = P*hh + H; P *= pp; }
      pp = __shfl(P, (lane - 32) & 63, 64);
      hh = __shfl(H, (lane - 32) & 63, 64);
      if (q >= 2){ H = P*hh + H; P *= pp; }
      // exclusive prefix for this q
      float pe = __shfl(P, (lane - 16) & 63, 64);
      float he = __shfl(H, (lane - 16) & 63, 64);
      if (q == 0){ pe = 1.f; he = 0.f; }
      // tile totals broadcast (q==3 inclusive)
      float pb = __shfl(P, m + 48, 64);
      float hb = __shfl(H, m + 48, 64);

      float h = he, pa = pe;
      float ys[4], cs[4];
#pragma unroll
      for (int r = 0; r < 4; ++r){
        h = Ar[r]*h + Br[r];
        pa *= Ar[r];
        ys[r] = Cc[r]*h;
        cs[r] = Cc[r]*pa;
      }
      ypk[i][nt][0] = cvt_pk_bf16(ys[0], ys[1]);
      ypk[i][nt][1] = cvt_pk_bf16(ys[2], ys[3]);
      cpk[i][nt][0] = cvt_pk_bf16(cs[0], cs[1]);
      cpk[i][nt][1] = cvt_pk_bf16(cs[2], cs[3]);

      pe_t[i][nt] = pa_run[nt];
      he_t[i][nt] = ha_run[nt];
      ha_run[nt] = pb*ha_run[nt] + hb;
      pa_run[nt] *= pb;
    }
  }
  // publish wave totals per n (identical across q; q==0 writes)
  if (q == 0){
#pragma unroll
    for (int nt = 0; nt < 2; ++nt){
      sPw[wv][nt*16 + m] = pa_run[nt];
      sHw[wv][nt*16 + m] = ha_run[nt];
    }
  }
  __syncthreads();                           // sW dead from here

  // ---- Phase B: publish LOCAL aggregate, decoupled lookback (threads 0..31)
  if (tid < 32){
    float Pw[4], Hw[4];
#pragma unroll
    for (int w2 = 0; w2 < 4; ++w2){ Pw[w2] = sPw[w2][tid]; Hw[w2] = sHw[w2][tid]; }
    // block-local aggregate over the 4 waves
    float pb = 1.f, hb = 0.f;
#pragma unroll
    for (int w2 = 0; w2 < 4; ++w2){ hb = Pw[w2]*hb + Hw[w2]; pb *= Pw[w2]; }
    // single-word publish: [P|H]; validity = P bits != 0 (P>0, clamped)
    float pbc = fmaxf(pb, 1e-30f);
    __hip_atomic_store(Sbuf + (size_t)(by*16 + bx)*32 + tid,
        ((unsigned long long)__float_as_uint(pbc) << 32) |
         (unsigned long long)__float_as_uint(hb),
        __ATOMIC_RELAXED, __HIP_MEMORY_SCOPE_AGENT);
    // gather ALL predecessors' locals concurrently. Backoff sleep: waiters
    // must NOT flood L2 with polls -- that starves workers' xp loads and
    // creates the straggler tail (R13 theory).
    float S = 0.f;
    const int cnt = bx & 7;                // # predecessors within batch row
    if (cnt){
      const int j0 = bx & ~7;
      unsigned long long v0=0,v1=0,v2=0,v3=0,v4=0,v5=0,v6=0;
      unsigned got = 0;
      int spin = 0;
      const unsigned all = (1u << cnt) - 1u;
      const unsigned long long* base = Sbuf + (size_t)(by*16 + j0)*32 + tid;
      for (;;){
#define LOOKBACK(J, V)                                                          \
        if (J < cnt && !(got & (1u << J))){                                     \
          unsigned long long a = __hip_atomic_load(base + (size_t)J*32,         \
              __ATOMIC_RELAXED, __HIP_MEMORY_SCOPE_AGENT);                      \
          if ((unsigned)(a >> 32) != 0u){ V = a; got |= 1u << J; }              \
        }
        LOOKBACK(0, v0) LOOKBACK(1, v1) LOOKBACK(2, v2) LOOKBACK(3, v3)
        LOOKBACK(4, v4) LOOKBACK(5, v5) LOOKBACK(6, v6)
#undef LOOKBACK
        if (got == all) break;
        if (spin < 4)       __builtin_amdgcn_s_sleep(2);
        else if (spin < 8)  __builtin_amdgcn_s_sleep(8);
        else                __builtin_amdgcn_s_sleep(32);
        ++spin;
      }
      // ordered composition j0..bx-1: S = P_j*S + H_j
#define COMPOSE(J, V)                                                           \
      if (J < cnt) S = __uint_as_float((unsigned)(V >> 32))*S +                 \
                       __uint_as_float((unsigned)V);
      COMPOSE(0, v0) COMPOSE(1, v1) COMPOSE(2, v2) COMPOSE(3, v3)
      COMPOSE(4, v4) COMPOSE(5, v5) COMPOSE(6, v6)
#undef COMPOSE
    }
    // per-wave init states
    float s = S;
#pragma unroll
    for (int w2 = 0; w2 < 4; ++w2){
      sIw[w2][tid] = s;
      s = Pw[w2]*s + Hw[w2];
    }
  }
  __syncthreads();                           // sYT (alias of sW) live from here

  // ---- Phase C: fixup + transpose + store
  float iw[2];
#pragma unroll
  for (int nt = 0; nt < 2; ++nt) iw[nt] = sIw[wv][nt*16 + m];
#pragma unroll
  for (int i = 0; i < 4; ++i){
    const int tile = bx*16 + wv*4 + i;
#pragma unroll
    for (int nt = 0; nt < 2; ++nt){
      float it = pe_t[i][nt]*iw[nt] + he_t[i][nt];
#pragma unroll
      for (int j2 = 0; j2 < 2; ++j2){
        unsigned yp = ypk[i][nt][j2], cp = cpk[i][nt][j2];
        float y0 = __uint_as_float(yp << 16);
        float y1 = __uint_as_float(yp & 0xffff0000u);
        float c0 = __uint_as_float(cp << 16);
        float c1 = __uint_as_float(cp & 0xffff0000u);
        sYT[(q*4 + j2*2 + 0)*40 + nt*16 + m] = f2b(y0 + c0*it);
        sYT[(q*4 + j2*2 + 1)*40 + nt*16 + m] = f2b(y1 + c1*it);
      }
    }
    short8 yv = *(const short8*)&sYT[m*40 + q*8];
    *(short8*)(ybp + (size_t)tile*32768 + (size_t)by*512 + (size_t)lane*8) = yv;
  }
}

// ---------------- 3. output projection ----------------
// grid NTILE=256, block 256. Wave wv: kk in [wv*16, wv*16+16), all 8 d-tiles.
__global__ void outproj_kernel(const unsigned short* __restrict__ ybp,
                               const unsigned short* __restrict__ Wop,
                               const float* __restrict__ b_out,
                               float* __restrict__ out){
  __shared__ float red[4*2048];
  const int tid  = threadIdx.x;
  const int lane = tid & 63;
  const int wv   = tid >> 6;
  const int m    = lane & 15;
  const int q    = lane >> 4;
  const int tile = blockIdx.x;

  floatx4 acc[8];
#pragma unroll
  for (int dt = 0; dt < 8; ++dt) acc[dt] = (floatx4){0.f,0.f,0.f,0.f};

  const unsigned short* aP = ybp + (size_t)tile*32768 + lane*8;
  const unsigned short* bP = Wop + (size_t)lane*8;
#pragma unroll 4
  for (int kk = wv*16; kk < wv*16 + 16; ++kk){
    short8 af = *(const short8*)(aP + (size_t)kk*512);
#pragma unroll
    for (int dt = 0; dt < 8; ++dt){
      short8 bf = *(const short8*)(bP + (size_t)dt*32768 + (size_t)kk*512);
      acc[dt] = __builtin_amdgcn_mfma_f32_16x16x32_bf16(af, bf, acc[dt], 0, 0, 0);
    }
  }
#pragma unroll
  for (int dt = 0; dt < 8; ++dt)
#pragma unroll
    for (int r = 0; r < 4; ++r)
      red[wv*2048 + (q*4 + r)*128 + dt*16 + m] = acc[dt][r];
  __syncthreads();
#pragma unroll
  for (int i = 0; i < 8; ++i){
    int idx = i*256 + tid;                        // 0..2047 = tl*128 + d
    float s = red[idx] + red[2048 + idx] + red[4096 + idx] + red[6144 + idx];
    int tl = idx >> 7, d = idx & 127;
    out[(size_t)(tile*16 + tl)*DDIM + d] = s + b_out[d];
  }
}

extern "C" void kernel_launch(void* const* d_in, const int* in_sizes, int n_in,
                              void* d_out, int out_size, void* d_ws, size_t ws_size,
                              hipStream_t stream) {
  const float* x     = (const float*)d_in[0];
  const float* W_B   = (const float*)d_in[1];
  const float* b_B   = (const float*)d_in[2];
  const float* W_C   = (const float*)d_in[3];
  const float* b_C   = (const float*)d_in[4];
  const float* W_dt  = (const float*)d_in[5];
  const float* b_dt  = (const float*)d_in[6];
  const float* A_log = (const float*)d_in[7];
  const float* W_out = (const float*)d_in[8];
  const float* b_out = (const float*)d_in[9];
  float* out = (float*)d_out;

  char* w = (char*)d_ws;
  unsigned short* xp    = (unsigned short*)(w + 0x0000000);  // 1 MB
  unsigned short* Wp3   = (unsigned short*)(w + 0x0100000);  // 1.5 MB
  unsigned short* Wop   = (unsigned short*)(w + 0x0280000);  // 0.5 MB
  float*          Aval  = (float*)         (w + 0x0300000);  // 8 KB
  unsigned short* ybp   = (unsigned short*)(w + 0x0310000);  // 16 MB
  unsigned long long* Sbuf = (unsigned long long*)(w + 0x1310000); // 256 KB
  // total ~19.7 MB

  prep_kernel<<<384, 256, 0, stream>>>(
      x, W_B, W_C, W_dt, A_log, W_out, xp, Wp3, Wop, Aval, Sbuf);

  projscan_kernel<<<dim3(16, 64), 256, 0, stream>>>(
      xp, Wp3, b_B, b_dt, b_C, Aval, Sbuf, ybp);

  outproj_kernel<<<NTILE, 256, 0, stream>>>(ybp, Wop, b_out, out);
}